// Round 2
// 90.884 us; speedup vs baseline: 1.1132x; 1.1132x over previous
//
#include <hip/hip_runtime.h>
#include <math.h>

// Problem constants (fixed by reference setup_inputs)
constexpr int B_ = 8;
constexpr int N_ = 2000;
constexpr int C_ = 81;
constexpr int BN = B_ * N_;

// d_out flat layout (element offsets), reference return order:
// nms_reg, nms_cls, rcnn_reg_adj, probs, reg_out, cls_out, keep
constexpr int O0 = 0;                 // nms_reg      B*N*4 = 64000
constexpr int O1 = 64000;             // nms_cls      B*N*2 = 32000
constexpr int O2 = 96000;             // rcnn_reg_adj B*N*4 = 64000
constexpr int O3 = 160000;            // probs        B*N*81 = 1296000
constexpr int O4 = 1456000;           // reg_out      B*N*4 = 64000
constexpr int O5 = 1520000;           // cls_out      B*N*81 = 1296000
constexpr int O6 = 2816000;           // keep         B*N   = 16000

// ---------------------------------------------------------------------------
// Kernel 1: per-box softmax, argmax (first occurrence on probs), score,
// reg adjust, keep init. One wave per box.
// Speculatively writes cls_out = probs and reg_out = adj for class>0 boxes
// (classnms only zeroes suppressed rows). Class-0 rows zeroed here.
// (clsArg, score) packed into one int2 for the classnms gather.
// ---------------------------------------------------------------------------
__global__ __launch_bounds__(256) void prep_kernel(
    const float* __restrict__ nms_reg, const float* __restrict__ nms_cls,
    const float* __restrict__ rcnn_reg, const float* __restrict__ rcnn_cls,
    const int* __restrict__ reduction,
    float* __restrict__ out, int2* __restrict__ packed)
{
    int gid  = blockIdx.x * blockDim.x + threadIdx.x;
    int wave = gid >> 6;
    int lane = threadIdx.x & 63;
    if (wave >= BN) return;

    // coalesced passthrough copies: nms_reg 16000 float4, nms_cls 8000 float4
    if (gid < 16000) {
        ((float4*)(out + O0))[gid] = ((const float4*)nms_reg)[gid];
    } else if (gid < 24000) {
        int g = gid - 16000;
        ((float4*)(out + O1))[g] = ((const float4*)nms_cls)[g];
    }

    const float* lg = rcnn_cls + (size_t)wave * C_;
    float x0 = lg[lane];
    float x1 = (lane < C_ - 64) ? lg[lane + 64] : -INFINITY;

    float m = fmaxf(x0, x1);
    for (int off = 32; off; off >>= 1) m = fmaxf(m, __shfl_xor(m, off, 64));

    float e0 = expf(x0 - m);
    float e1 = (lane < C_ - 64) ? expf(x1 - m) : 0.0f;
    float s = e0 + e1;
    for (int off = 32; off; off >>= 1) s += __shfl_xor(s, off, 64);

    float p0 = e0 / s;
    float p1 = e1 / s;

    // argmax on probs, first occurrence (larger value; tie -> smaller index)
    float v = p0; int idx = lane;
    if (lane < C_ - 64 && p1 > p0) { v = p1; idx = lane + 64; }
    for (int off = 32; off; off >>= 1) {
        float ov = __shfl_xor(v, off, 64);
        int   oi = __shfl_xor(idx, off, 64);
        if (ov > v || (ov == v && oi < idx)) { v = ov; idx = oi; }
    }
    bool valid = (idx != 0);

    // probs + speculative cls_out (zeros for class-0 boxes)
    float* probs = out + O3 + (size_t)wave * C_;
    float* co    = out + O5 + (size_t)wave * C_;
    probs[lane] = p0;
    co[lane]    = valid ? p0 : 0.0f;
    if (lane < C_ - 64) {
        probs[lane + 64] = p1;
        co[lane + 64]    = valid ? p1 : 0.0f;
    }

    // rcnn_reg_adj = rcnn_reg + (floor/ceil(nms_reg*red))/red ; reg_out spec.
    if (lane < 4) {
        float red = (float)reduction[0];
        float t = nms_reg[(size_t)wave * 4 + lane] * red;
        float r = (lane < 2) ? floorf(t) : ceilf(t);
        float adj = rcnn_reg[(size_t)wave * 4 + lane] + r / red;
        out[O2 + (size_t)wave * 4 + lane] = adj;
        out[O4 + (size_t)wave * 4 + lane] = valid ? adj : 0.0f;
    }

    if (lane == 0) {
        packed[wave] = make_int2(idx, __float_as_int(v));
        out[O6 + wave] = 0.0f;   // keep init; classnms sets kept ones to 1
    }
}

// ---------------------------------------------------------------------------
// Kernel 2: fused gather + sort + greedy NMS + suppressed-row zeroing.
// One block (256 threads) per (image, class>0).
//   gather: 4 waves scan 500-entry strips (one int2 load each), ballot-
//           compact into LDS
//   sort:   256-thread rank counting, deterministic == stable argsort
//   nms:    k<=64 fast path — parallel all-pairs suppressor masks in LDS
//           (supm[j] = set of i<j with IoU>thr), then single-thread greedy:
//           ascending j, clear j iff (supm[j] & keep) != 0. Exact reference
//           IoU arithmetic. k>64 fallback — proven wave-0 register-chunk path.
//   write:  keep=1 for kept boxes; zero reg_out/cls_out rows for suppressed
//           (kept rows already hold adj/probs from prep).
// ---------------------------------------------------------------------------
__global__ __launch_bounds__(256) void classnms_kernel(
    const int2* __restrict__ packed, float* __restrict__ out)
{
    __shared__ int   list[N_];   // gather ids; reused as keep flags (sorted order)
    __shared__ float sc[N_];     // scores; reused as box stage + sup masks
    __shared__ int   srt[N_];
    __shared__ int   cnt;
    __shared__ unsigned long long keep_sh;

    int b = blockIdx.x / (C_ - 1);
    int c = blockIdx.x % (C_ - 1) + 1;
    int tid  = threadIdx.x;
    int lane = tid & 63;
    int w    = tid >> 6;         // wave id 0..3

    if (tid == 0) cnt = 0;
    __syncthreads();

    // ---- gather: wave w scans strip [w*500, (w+1)*500) ----
    const int STRIP = N_ / 4;    // 500
    #pragma unroll
    for (int it = 0; it < (STRIP + 63) / 64; it++) {
        int n = w * STRIP + it * 64 + lane;
        bool m = false;
        float sv = 0.0f;
        if (n < (w + 1) * STRIP) {
            int2 pc = packed[b * N_ + n];
            m  = (pc.x == c);
            sv = __int_as_float(pc.y);
        }
        unsigned long long bal = __ballot(m);
        int nset = __popcll(bal);
        int base = 0;
        if (lane == 0 && nset) base = atomicAdd(&cnt, nset);
        base = __shfl(base, 0, 64);
        if (m) {
            int pos = base + __popcll(bal & ((1ull << lane) - 1ull));
            list[pos] = n;
            sc[pos]   = sv;
        }
    }
    __syncthreads();
    int k = cnt;
    if (k == 0) return;          // uniform exit

    // ---- rank sort: (score desc, idx asc) ----
    for (int t = tid; t < k; t += 256) {
        int   my  = list[t];
        float mys = sc[t];
        int rank = 0;
        for (int j = 0; j < k; j++) {
            float os = sc[j];
            rank += (os > mys) || (os == mys && list[j] < my);
        }
        srt[rank] = my;
    }
    __syncthreads();

    const float* boxes4 = out + O2;
    float off = (float)c * 100000.0f;    // exact integer < 2^23

    if (k <= 64) {
        // ---- fast path: parallel all-pairs + scalar greedy recurrence ----
        float* bt  = sc;
        float* bl  = sc + 64;
        float* bb2 = sc + 128;
        float* br  = sc + 192;
        float* ba  = sc + 256;
        unsigned long long* supm = (unsigned long long*)(sc + 320); // 8B-aligned

        if (tid < k) {
            float4 p = ((const float4*)boxes4)[b * N_ + srt[tid]];
            float t = p.x + off, l = p.y + off, bo = p.z + off, r = p.w + off;
            bt[tid]  = t;  bl[tid] = l;  bb2[tid] = bo;  br[tid] = r;
            ba[tid]  = (bo - t) * (r - l);
        }
        __syncthreads();

        if (tid < k) {
            float tj = bt[tid], lj = bl[tid], bj = bb2[tid], rj = br[tid], aj = ba[tid];
            unsigned long long msk = 0ull;
            for (int i = 0; i < k; i++) {       // LDS broadcast reads
                float ti = bt[i], li = bl[i], bi = bb2[i], ri = br[i], ai = ba[i];
                float it2 = fmaxf(ti, tj), il2 = fmaxf(li, lj);
                float ib = fminf(bi, bj), ir = fminf(ri, rj);
                float inter = fmaxf(ib - it2, 0.0f) * fmaxf(ir - il2, 0.0f);
                float uni = ai + aj - inter;
                bool sup = (inter / fmaxf(uni, 1e-9f) > 0.5f) && (i < tid);
                msk |= sup ? (1ull << i) : 0ull;
            }
            supm[tid] = msk;    // suppressors of tid (bits i < tid)
        }
        __syncthreads();

        if (tid == 0) {
            // greedy: ascending j; j dies iff some already-kept i<j suppresses it
            unsigned long long keep = (k == 64) ? ~0ull : ((1ull << k) - 1ull);
            for (int j = 1; j < k; j++)
                if (supm[j] & keep) keep &= ~(1ull << j);
            keep_sh = keep;
        }
        __syncthreads();
        unsigned long long keep = keep_sh;
        for (int p = tid; p < k; p += 256) list[p] = (int)((keep >> p) & 1ull);
    } else {
        // ---- fallback: original wave-0 register-chunk NMS ----
        if (w == 0) {
            float t0 = 0, l0 = 0, bb0 = 0, r0 = 0, a0 = 0;
            if (lane < k) {
                const float* p = boxes4 + (size_t)(b * N_ + srt[lane]) * 4;
                t0 = p[0] + off; l0 = p[1] + off; bb0 = p[2] + off; r0 = p[3] + off;
                a0 = (bb0 - t0) * (r0 - l0);
            }

            int nch = (k + 63) >> 6;
            unsigned int keepm = 0;
            for (int ch = 0; ch < nch; ch++) if (ch * 64 + lane < k) keepm |= (1u << ch);

            for (int i = 0; i < k; i++) {
                int ich = i >> 6, il = i & 63;
                unsigned int wi = __shfl(keepm, il, 64);
                if (!((wi >> ich) & 1)) continue;    // wave-uniform

                float ti, li, bi, ri, ai;
                if (ich == 0) {
                    ti = __shfl(t0, il, 64); li = __shfl(l0, il, 64);
                    bi = __shfl(bb0, il, 64); ri = __shfl(r0, il, 64);
                    ai = __shfl(a0, il, 64);
                } else {
                    const float* p = boxes4 + (size_t)(b * N_ + srt[i]) * 4;
                    ti = p[0] + off; li = p[1] + off; bi = p[2] + off; ri = p[3] + off;
                    ai = (bi - ti) * (ri - li);
                }

                for (int ch = ich; ch < nch; ch++) {
                    int j = ch * 64 + lane;
                    if (j <= i || j >= k) continue;
                    if (!((keepm >> ch) & 1)) continue;
                    float tj, lj, bj, rj, aj;
                    if (ch == 0) { tj = t0; lj = l0; bj = bb0; rj = r0; aj = a0; }
                    else {
                        const float* p = boxes4 + (size_t)(b * N_ + srt[j]) * 4;
                        tj = p[0] + off; lj = p[1] + off; bj = p[2] + off; rj = p[3] + off;
                        aj = (bj - tj) * (rj - lj);
                    }
                    float it2 = fmaxf(ti, tj), il2 = fmaxf(li, lj);
                    float ib = fminf(bi, bj), ir = fminf(ri, rj);
                    float inter = fmaxf(ib - it2, 0.0f) * fmaxf(ir - il2, 0.0f);
                    float uni = ai + aj - inter;
                    if (inter / fmaxf(uni, 1e-9f) > 0.5f) keepm &= ~(1u << ch);
                }
            }

            for (int ch = 0; ch < nch; ch++) {
                int j = ch * 64 + lane;
                if (j < k) list[j] = (keepm >> ch) & 1;
            }
        }
    }
    __syncthreads();

    // ---- output write: kept -> keep=1; suppressed -> zero reg_out/cls_out ----
    for (int p = tid; p < k; p += 256) {
        int g = b * N_ + srt[p];
        if (list[p]) out[O6 + g] = 1.0f;
        else         ((float4*)(out + O4))[g] = float4{0.f, 0.f, 0.f, 0.f};
    }
    for (int idx = tid; idx < k * C_; idx += 256) {
        int p = idx / C_, e = idx - p * C_;
        if (!list[p]) {
            int g = b * N_ + srt[p];
            out[O5 + (size_t)g * C_ + e] = 0.0f;
        }
    }
}

// ---------------------------------------------------------------------------
extern "C" void kernel_launch(void* const* d_in, const int* in_sizes, int n_in,
                              void* d_out, int out_size, void* d_ws, size_t ws_size,
                              hipStream_t stream)
{
    const float* nms_reg   = (const float*)d_in[0];
    const float* nms_cls   = (const float*)d_in[1];
    const float* rcnn_reg  = (const float*)d_in[2];
    const float* rcnn_cls  = (const float*)d_in[3];
    const int*   reduction = (const int*)d_in[4];
    float* out = (float*)d_out;

    int2* packed = (int2*)d_ws;                  // 16000 int2 = 128 KB

    prep_kernel<<<(BN * 64) / 256, 256, 0, stream>>>(
        nms_reg, nms_cls, rcnn_reg, rcnn_cls, reduction, out, packed);
    classnms_kernel<<<B_ * (C_ - 1), 256, 0, stream>>>(packed, out);
}

// Round 3
// 89.196 us; speedup vs baseline: 1.1343x; 1.0189x over previous
//
#include <hip/hip_runtime.h>
#include <math.h>

// Problem constants (fixed by reference setup_inputs)
constexpr int B_ = 8;
constexpr int N_ = 2000;
constexpr int C_ = 81;
constexpr int BN = B_ * N_;

// d_out flat layout (element offsets), reference return order:
// nms_reg, nms_cls, rcnn_reg_adj, probs, reg_out, cls_out, keep
constexpr int O0 = 0;                 // nms_reg      B*N*4 = 64000
constexpr int O1 = 64000;             // nms_cls      B*N*2 = 32000
constexpr int O2 = 96000;             // rcnn_reg_adj B*N*4 = 64000
constexpr int O3 = 160000;            // probs        B*N*81 = 1296000
constexpr int O4 = 1456000;           // reg_out      B*N*4 = 64000
constexpr int O5 = 1520000;           // cls_out      B*N*81 = 1296000
constexpr int O6 = 2816000;           // keep         B*N   = 16000

// ---------------------------------------------------------------------------
// Kernel 1: per-box softmax, argmax (first occurrence on probs), score,
// reg adjust. One wave per box.
// Speculatively writes cls_out = probs and reg_out = adj for class>0 boxes
// (classnms only zeroes suppressed rows). Class-0 rows zeroed here.
// keep init done as coalesced float4 zeros in the passthrough region.
// (clsArg, score) packed into one int2 for the classnms gather.
// ---------------------------------------------------------------------------
__global__ __launch_bounds__(256) void prep_kernel(
    const float* __restrict__ nms_reg, const float* __restrict__ nms_cls,
    const float* __restrict__ rcnn_reg, const float* __restrict__ rcnn_cls,
    const int* __restrict__ reduction,
    float* __restrict__ out, int2* __restrict__ packed)
{
    int gid  = blockIdx.x * blockDim.x + threadIdx.x;
    int wave = gid >> 6;
    int lane = threadIdx.x & 63;
    if (wave >= BN) return;

    // coalesced passthrough: nms_reg 16000 float4, nms_cls 8000 float4,
    // keep-init 4000 float4 of zeros
    if (gid < 16000) {
        ((float4*)(out + O0))[gid] = ((const float4*)nms_reg)[gid];
    } else if (gid < 24000) {
        int g = gid - 16000;
        ((float4*)(out + O1))[g] = ((const float4*)nms_cls)[g];
    } else if (gid < 28000) {
        int g = gid - 24000;
        ((float4*)(out + O6))[g] = float4{0.f, 0.f, 0.f, 0.f};
    }

    const float* lg = rcnn_cls + (size_t)wave * C_;
    float x0 = lg[lane];
    float x1 = (lane < C_ - 64) ? lg[lane + 64] : -INFINITY;

    float m = fmaxf(x0, x1);
    for (int off = 32; off; off >>= 1) m = fmaxf(m, __shfl_xor(m, off, 64));

    float e0 = expf(x0 - m);
    float e1 = (lane < C_ - 64) ? expf(x1 - m) : 0.0f;
    float s = e0 + e1;
    for (int off = 32; off; off >>= 1) s += __shfl_xor(s, off, 64);

    float p0 = e0 / s;
    float p1 = e1 / s;

    // argmax on probs, first occurrence (larger value; tie -> smaller index)
    float v = p0; int idx = lane;
    if (lane < C_ - 64 && p1 > p0) { v = p1; idx = lane + 64; }
    for (int off = 32; off; off >>= 1) {
        float ov = __shfl_xor(v, off, 64);
        int   oi = __shfl_xor(idx, off, 64);
        if (ov > v || (ov == v && oi < idx)) { v = ov; idx = oi; }
    }
    bool valid = (idx != 0);

    // probs + speculative cls_out (zeros for class-0 boxes)
    float* probs = out + O3 + (size_t)wave * C_;
    float* co    = out + O5 + (size_t)wave * C_;
    probs[lane] = p0;
    co[lane]    = valid ? p0 : 0.0f;
    if (lane < C_ - 64) {
        probs[lane + 64] = p1;
        co[lane + 64]    = valid ? p1 : 0.0f;
    }

    // rcnn_reg_adj = rcnn_reg + (floor/ceil(nms_reg*red))/red ; reg_out spec.
    if (lane < 4) {
        float red = (float)reduction[0];
        float t = nms_reg[(size_t)wave * 4 + lane] * red;
        float r = (lane < 2) ? floorf(t) : ceilf(t);
        float adj = rcnn_reg[(size_t)wave * 4 + lane] + r / red;
        out[O2 + (size_t)wave * 4 + lane] = adj;
        out[O4 + (size_t)wave * 4 + lane] = valid ? adj : 0.0f;
    }

    if (lane == 0) {
        packed[wave] = make_int2(idx, __float_as_int(v));
    }
}

// ---------------------------------------------------------------------------
// Kernel 2: fused gather + sort + greedy NMS + suppressed-row zeroing.
// One block (256 threads) per (image, class>0).
//   gather: 4 waves scan 500-entry strips with int4 loads (2 entries/lane,
//           4 rounds), all 8 ballots collected in registers, ONE LDS atomic
//           per wave, positions from ballot prefix sums
//   sort:   256-thread rank counting, deterministic == stable argsort
//   nms:    k<=64 fast path — parallel all-pairs suppressor masks in LDS
//           (supm[j] = set of i<j with IoU>thr), then single-thread greedy:
//           ascending j, clear j iff (supm[j] & keep) != 0. Exact reference
//           IoU arithmetic. k>64 fallback — proven wave-0 register-chunk path.
//   write:  keep=1 for kept boxes; zero reg_out/cls_out rows for suppressed
//           (kept rows already hold adj/probs from prep).
// ---------------------------------------------------------------------------
__global__ __launch_bounds__(256) void classnms_kernel(
    const int2* __restrict__ packed, float* __restrict__ out)
{
    __shared__ int   list[N_];   // gather ids; reused as keep flags (sorted order)
    __shared__ float sc[N_];     // scores; reused as box stage + sup masks
    __shared__ int   srt[N_];
    __shared__ int   cnt;
    __shared__ unsigned long long keep_sh;

    int b = blockIdx.x / (C_ - 1);
    int c = blockIdx.x % (C_ - 1) + 1;
    int tid  = threadIdx.x;
    int lane = tid & 63;
    int w    = tid >> 6;         // wave id 0..3

    if (tid == 0) cnt = 0;
    __syncthreads();

    // ---- gather: wave w scans strip [w*500, (w+1)*500), 2 entries/lane ----
    const int STRIP = N_ / 4;    // 500
    {
        float sv[8];
        unsigned long long bal[8];
        bool mv[8];
        #pragma unroll
        for (int it = 0; it < 4; it++) {
            int n0 = w * STRIP + it * 128 + lane * 2;
            bool m0 = false, m1 = false;
            float s0 = 0.f, s1 = 0.f;
            if (n0 < (w + 1) * STRIP) {        // n0 <= 498, so n0+1 in-image
                int4 q = *(const int4*)(packed + b * N_ + n0);
                m0 = (q.x == c);  s0 = __int_as_float(q.y);
                m1 = (q.z == c) && (n0 + 1 < (w + 1) * STRIP);
                s1 = __int_as_float(q.w);
            }
            mv[it*2]   = m0;  sv[it*2]   = s0;  bal[it*2]   = __ballot(m0);
            mv[it*2+1] = m1;  sv[it*2+1] = s1;  bal[it*2+1] = __ballot(m1);
        }
        int total = 0;
        #pragma unroll
        for (int s = 0; s < 8; s++) total += __popcll(bal[s]);
        int base = 0;
        if (lane == 0 && total) base = atomicAdd(&cnt, total);
        base = __shfl(base, 0, 64);
        unsigned long long below = (1ull << lane) - 1ull;
        int pre = 0;
        #pragma unroll
        for (int s = 0; s < 8; s++) {
            if (mv[s]) {
                int pos = base + pre + __popcll(bal[s] & below);
                int n = w * STRIP + (s >> 1) * 128 + lane * 2 + (s & 1);
                list[pos] = n;
                sc[pos]   = sv[s];
            }
            pre += __popcll(bal[s]);
        }
    }
    __syncthreads();
    int k = cnt;
    if (k == 0) return;          // uniform exit

    // ---- rank sort: (score desc, idx asc) ----
    for (int t = tid; t < k; t += 256) {
        int   my  = list[t];
        float mys = sc[t];
        int rank = 0;
        for (int j = 0; j < k; j++) {
            float os = sc[j];
            rank += (os > mys) || (os == mys && list[j] < my);
        }
        srt[rank] = my;
    }
    __syncthreads();

    const float* boxes4 = out + O2;
    float off = (float)c * 100000.0f;    // exact integer < 2^23

    if (k <= 64) {
        // ---- fast path: parallel all-pairs + scalar greedy recurrence ----
        float* bt  = sc;
        float* bl  = sc + 64;
        float* bb2 = sc + 128;
        float* br  = sc + 192;
        float* ba  = sc + 256;
        unsigned long long* supm = (unsigned long long*)(sc + 320); // 8B-aligned

        if (tid < k) {
            float4 p = ((const float4*)boxes4)[b * N_ + srt[tid]];
            float t = p.x + off, l = p.y + off, bo = p.z + off, r = p.w + off;
            bt[tid]  = t;  bl[tid] = l;  bb2[tid] = bo;  br[tid] = r;
            ba[tid]  = (bo - t) * (r - l);
        }
        __syncthreads();

        if (tid < k) {
            float tj = bt[tid], lj = bl[tid], bj = bb2[tid], rj = br[tid], aj = ba[tid];
            unsigned long long msk = 0ull;
            for (int i = 0; i < k; i++) {       // LDS broadcast reads
                float ti = bt[i], li = bl[i], bi = bb2[i], ri = br[i], ai = ba[i];
                float it2 = fmaxf(ti, tj), il2 = fmaxf(li, lj);
                float ib = fminf(bi, bj), ir = fminf(ri, rj);
                float inter = fmaxf(ib - it2, 0.0f) * fmaxf(ir - il2, 0.0f);
                float uni = ai + aj - inter;
                bool sup = (inter / fmaxf(uni, 1e-9f) > 0.5f) && (i < tid);
                msk |= sup ? (1ull << i) : 0ull;
            }
            supm[tid] = msk;    // suppressors of tid (bits i < tid)
        }
        __syncthreads();

        if (tid == 0) {
            // greedy: ascending j; j dies iff some already-kept i<j suppresses it
            unsigned long long keep = (k == 64) ? ~0ull : ((1ull << k) - 1ull);
            for (int j = 1; j < k; j++)
                if (supm[j] & keep) keep &= ~(1ull << j);
            keep_sh = keep;
        }
        __syncthreads();
        unsigned long long keep = keep_sh;
        for (int p = tid; p < k; p += 256) list[p] = (int)((keep >> p) & 1ull);
    } else {
        // ---- fallback: original wave-0 register-chunk NMS ----
        if (w == 0) {
            float t0 = 0, l0 = 0, bb0 = 0, r0 = 0, a0 = 0;
            if (lane < k) {
                const float* p = boxes4 + (size_t)(b * N_ + srt[lane]) * 4;
                t0 = p[0] + off; l0 = p[1] + off; bb0 = p[2] + off; r0 = p[3] + off;
                a0 = (bb0 - t0) * (r0 - l0);
            }

            int nch = (k + 63) >> 6;
            unsigned int keepm = 0;
            for (int ch = 0; ch < nch; ch++) if (ch * 64 + lane < k) keepm |= (1u << ch);

            for (int i = 0; i < k; i++) {
                int ich = i >> 6, il = i & 63;
                unsigned int wi = __shfl(keepm, il, 64);
                if (!((wi >> ich) & 1)) continue;    // wave-uniform

                float ti, li, bi, ri, ai;
                if (ich == 0) {
                    ti = __shfl(t0, il, 64); li = __shfl(l0, il, 64);
                    bi = __shfl(bb0, il, 64); ri = __shfl(r0, il, 64);
                    ai = __shfl(a0, il, 64);
                } else {
                    const float* p = boxes4 + (size_t)(b * N_ + srt[i]) * 4;
                    ti = p[0] + off; li = p[1] + off; bi = p[2] + off; ri = p[3] + off;
                    ai = (bi - ti) * (ri - li);
                }

                for (int ch = ich; ch < nch; ch++) {
                    int j = ch * 64 + lane;
                    if (j <= i || j >= k) continue;
                    if (!((keepm >> ch) & 1)) continue;
                    float tj, lj, bj, rj, aj;
                    if (ch == 0) { tj = t0; lj = l0; bj = bb0; rj = r0; aj = a0; }
                    else {
                        const float* p = boxes4 + (size_t)(b * N_ + srt[j]) * 4;
                        tj = p[0] + off; lj = p[1] + off; bj = p[2] + off; rj = p[3] + off;
                        aj = (bj - tj) * (rj - lj);
                    }
                    float it2 = fmaxf(ti, tj), il2 = fmaxf(li, lj);
                    float ib = fminf(bi, bj), ir = fminf(ri, rj);
                    float inter = fmaxf(ib - it2, 0.0f) * fmaxf(ir - il2, 0.0f);
                    float uni = ai + aj - inter;
                    if (inter / fmaxf(uni, 1e-9f) > 0.5f) keepm &= ~(1u << ch);
                }
            }

            for (int ch = 0; ch < nch; ch++) {
                int j = ch * 64 + lane;
                if (j < k) list[j] = (keepm >> ch) & 1;
            }
        }
    }
    __syncthreads();

    // ---- output write: kept -> keep=1; suppressed -> zero reg_out/cls_out ----
    for (int p = tid; p < k; p += 256) {
        int g = b * N_ + srt[p];
        if (list[p]) out[O6 + g] = 1.0f;
        else         ((float4*)(out + O4))[g] = float4{0.f, 0.f, 0.f, 0.f};
    }
    for (int idx = tid; idx < k * C_; idx += 256) {
        int p = idx / C_, e = idx - p * C_;
        if (!list[p]) {
            int g = b * N_ + srt[p];
            out[O5 + (size_t)g * C_ + e] = 0.0f;
        }
    }
}

// ---------------------------------------------------------------------------
extern "C" void kernel_launch(void* const* d_in, const int* in_sizes, int n_in,
                              void* d_out, int out_size, void* d_ws, size_t ws_size,
                              hipStream_t stream)
{
    const float* nms_reg   = (const float*)d_in[0];
    const float* nms_cls   = (const float*)d_in[1];
    const float* rcnn_reg  = (const float*)d_in[2];
    const float* rcnn_cls  = (const float*)d_in[3];
    const int*   reduction = (const int*)d_in[4];
    float* out = (float*)d_out;

    int2* packed = (int2*)d_ws;                  // 16000 int2 = 128 KB

    prep_kernel<<<(BN * 64) / 256, 256, 0, stream>>>(
        nms_reg, nms_cls, rcnn_reg, rcnn_cls, reduction, out, packed);
    classnms_kernel<<<B_ * (C_ - 1), 256, 0, stream>>>(packed, out);
}